// Round 2
// baseline (1215.088 us; speedup 1.0000x reference)
//
#include <hip/hip_runtime.h>
#include <stdint.h>
#include <math.h>

// ============================================================================
// ProposalDistribution: 4x fp32 GEMM [32768,512]x[512,512]^T -> exp ->
// per-row Gaussian-NLL quadratic coefficients -> JAX-threefry rejection sampler.
//
// PRNG semantics: jax_threefry_partitionable = True (JAX >= 0.4.36 default).
//   split(key,n)[i]      = threefry(key, (0,i))  -> both output words
//   random_bits(k,32,()) = tf(k,(0,0)).a XOR tf(k,(0,0)).b   <-- R1 fix (was .b)
// If validation fails with O(1) absmax on many rows, set PARTITIONABLE 0.
// ============================================================================
#ifndef PARTITIONABLE
#define PARTITIONABLE 1
#endif

#define TM 128          // rows per block
#define TN 128          // cols per phase
#define KT 16           // k per staging tile
#define KDIM 512
#define NT (KDIM / KT)  // 32 tiles
#define LOG_EPS (-13.815510557964274f)   // log(1e-6)

struct U2 { uint32_t a, b; };

__device__ __forceinline__ uint32_t rotl(uint32_t v, int d) {
  return (v << d) | (v >> (32 - d));
}

// Threefry-2x32, 20 rounds — exact JAX algorithm.
__device__ __forceinline__ U2 tf2x32(uint32_t k0, uint32_t k1, uint32_t x0, uint32_t x1) {
  const uint32_t k2 = k0 ^ k1 ^ 0x1BD11BDAu;
  x0 += k0; x1 += k1;
#define TFR(r) { x0 += x1; x1 = rotl(x1, r); x1 ^= x0; }
  TFR(13) TFR(15) TFR(26) TFR(6)
  x0 += k1; x1 += k2 + 1u;
  TFR(17) TFR(29) TFR(16) TFR(24)
  x0 += k2; x1 += k0 + 2u;
  TFR(13) TFR(15) TFR(26) TFR(6)
  x0 += k0; x1 += k1 + 3u;
  TFR(17) TFR(29) TFR(16) TFR(24)
  x0 += k1; x1 += k2 + 4u;
  TFR(13) TFR(15) TFR(26) TFR(6)
  x0 += k2; x1 += k0 + 5u;
#undef TFR
  U2 r; r.a = x0; r.b = x1; return r;
}

// JAX uniform [0,1): bitcast((bits>>9)|0x3f800000) - 1.0f
__device__ __forceinline__ float bits_to_u01(uint32_t b) {
  return __uint_as_float((b >> 9) | 0x3f800000u) - 1.0f;
}

__global__ __launch_bounds__(256, 1)
void fused_proposal_kernel(const float* __restrict__ gx, const float* __restrict__ gy,
                           const float* __restrict__ Wmux, const float* __restrict__ bmux,
                           const float* __restrict__ Wsgx, const float* __restrict__ bsgx,
                           const float* __restrict__ Wmuy, const float* __restrict__ bmuy,
                           const float* __restrict__ Wsgy, const float* __restrict__ bsgy,
                           float* __restrict__ out)
{
  __shared__ float Xs[KT][TM];    // k-major: conflict-free b128 reads
  __shared__ float Wms[KT][TN];
  __shared__ float Wss[KT][TN];
  __shared__ double red[TM][8];   // per-row sums: [A,I,M,Q] x {x-dist, y-dist}

  const int tid = threadIdx.x;
  const int tx = tid & 15;        // col-thread
  const int ty = tid >> 4;        // row-thread
  const int r0 = blockIdx.x * TM;
  const int lr = tid >> 2;        // staging row/col 0..63
  const int q4 = (tid & 3) << 2;  // staging k offset 0,4,8,12

  for (int i = tid; i < TM * 8; i += 256) ((double*)red)[i] = 0.0;

  for (int ph = 0; ph < 8; ++ph) {
    const int dist = ph >> 2;           // 0: x-dist, 1: y-dist
    const int c0 = (ph & 3) * TN;       // col tile base
    const float* __restrict__ Xg = dist ? gy : gx;
    const float* __restrict__ Wm = dist ? Wmuy : Wmux;
    const float* __restrict__ Wv = dist ? Wsgy : Wsgx;
    const float* __restrict__ bm = dist ? bmuy : bmux;
    const float* __restrict__ bv = dist ? bsgy : bsgx;

    float am[8][8], av[8][8];
#pragma unroll
    for (int r = 0; r < 8; ++r)
#pragma unroll
      for (int c = 0; c < 8; ++c) { am[r][c] = 0.0f; av[r][c] = 0.0f; }

    const float* xp0 = Xg + (size_t)(r0 + lr) * KDIM + q4;
    const float* xp1 = Xg + (size_t)(r0 + lr + 64) * KDIM + q4;
    const float* mp0 = Wm + (size_t)(c0 + lr) * KDIM + q4;
    const float* mp1 = Wm + (size_t)(c0 + lr + 64) * KDIM + q4;
    const float* vp0 = Wv + (size_t)(c0 + lr) * KDIM + q4;
    const float* vp1 = Wv + (size_t)(c0 + lr + 64) * KDIM + q4;

    // prefetch tile 0 into registers
    float4 xa = *(const float4*)(xp0);
    float4 xb = *(const float4*)(xp1);
    float4 ma = *(const float4*)(mp0);
    float4 mb = *(const float4*)(mp1);
    float4 va = *(const float4*)(vp0);
    float4 vb = *(const float4*)(vp1);

    for (int t = 0; t < NT; ++t) {
      __syncthreads();  // previous tile's readers done
      // transpose-store staged regs to k-major LDS
#define ST4(arr, col, v) { arr[q4+0][col]=v.x; arr[q4+1][col]=v.y; arr[q4+2][col]=v.z; arr[q4+3][col]=v.w; }
      ST4(Xs,  lr, xa)  ST4(Xs,  lr + 64, xb)
      ST4(Wms, lr, ma)  ST4(Wms, lr + 64, mb)
      ST4(Wss, lr, va)  ST4(Wss, lr + 64, vb)
#undef ST4
      __syncthreads();
      if (t + 1 < NT) {            // prefetch next tile: in flight during compute
        const int ko = (t + 1) * KT;
        xa = *(const float4*)(xp0 + ko);
        xb = *(const float4*)(xp1 + ko);
        ma = *(const float4*)(mp0 + ko);
        mb = *(const float4*)(mp1 + ko);
        va = *(const float4*)(vp0 + ko);
        vb = *(const float4*)(vp1 + ko);
      }
#pragma unroll
      for (int kk = 0; kk < KT; ++kk) {
        const float4 x0 = *(const float4*)&Xs[kk][ty * 8];
        const float4 x1 = *(const float4*)&Xs[kk][ty * 8 + 4];
        const float4 m0 = *(const float4*)&Wms[kk][tx * 4];
        const float4 m1 = *(const float4*)&Wms[kk][tx * 4 + 64];
        const float4 v0 = *(const float4*)&Wss[kk][tx * 4];
        const float4 v1 = *(const float4*)&Wss[kk][tx * 4 + 64];
        const float xr[8] = {x0.x, x0.y, x0.z, x0.w, x1.x, x1.y, x1.z, x1.w};
        const float wm[8] = {m0.x, m0.y, m0.z, m0.w, m1.x, m1.y, m1.z, m1.w};
        const float wv[8] = {v0.x, v0.y, v0.z, v0.w, v1.x, v1.y, v1.z, v1.w};
#pragma unroll
        for (int r = 0; r < 8; ++r)
#pragma unroll
          for (int c = 0; c < 8; ++c) {
            am[r][c] = fmaf(xr[r], wm[c], am[r][c]);
            av[r][c] = fmaf(xr[r], wv[c], av[r][c]);
          }
      }
    }

    // ---- epilogue: bias, exp, per-row quadratic-coefficient partials ----
    float bmr[8], bvr[8];
#pragma unroll
    for (int c = 0; c < 4; ++c) {
      bmr[c]     = bm[c0 + tx * 4 + c];
      bmr[4 + c] = bm[c0 + 64 + tx * 4 + c];
      bvr[c]     = bv[c0 + tx * 4 + c];
      bvr[4 + c] = bv[c0 + 64 + tx * 4 + c];
    }
#pragma unroll
    for (int r = 0; r < 8; ++r) {
      float pA = 0.f, pI = 0.f, pM = 0.f, pQ = 0.f;
#pragma unroll
      for (int c = 0; c < 8; ++c) {
        const float m = am[r][c] + bmr[c];
        const float s = av[r][c] + bvr[c];
        const float v = fmaxf(expf(s), 1e-6f);     // ref's fp32 'var'
        const float lg = fmaxf(s, LOG_EPS);        // log(max(exp(s),eps))
        const float inv = __builtin_amdgcn_rcpf(v);  // 1-ulp rcp
        pA += lg;
        pI += inv;
        pM += m * inv;
        pQ += m * m * inv;
      }
      // butterfly reduce over the 16 col-threads (same ty => same rows)
#pragma unroll
      for (int msk = 1; msk < 16; msk <<= 1) {
        pA += __shfl_xor(pA, msk);
        pI += __shfl_xor(pI, msk);
        pM += __shfl_xor(pM, msk);
        pQ += __shfl_xor(pQ, msk);
      }
      if (tx == 0) {
        double* rr = &red[ty * 8 + r][dist * 4];
        rr[0] += (double)pA; rr[1] += (double)pI;
        rr[2] += (double)pM; rr[3] += (double)pQ;
      }
    }
  }

  __syncthreads();

  // ---- fused rejection sampler: one thread per row, exact JAX threefry ----
  if (tid < TM) {
    const int grow = r0 + tid;
    const double Ax = red[tid][0], Ix = red[tid][1], Mx = red[tid][2], Qx = red[tid][3];
    const double Ay = red[tid][4], Iy = red[tid][5], My = red[tid][6], Qy = red[tid][7];

#if PARTITIONABLE
    // split(key(42), 32768)[row] = threefry((0,42),(0,row))
    U2 key = tf2x32(0u, 42u, 0u, (uint32_t)grow);
#else
    // legacy split: counts=iota(2N) halved, concat-reshape interleave
    U2 key;
    {
      const uint32_t j = (uint32_t)grow;
      if (j < 16384u) {
        key.a = tf2x32(0u, 42u, 2u * j,      2u * j + 32768u).a;
        key.b = tf2x32(0u, 42u, 2u * j + 1u, 2u * j + 32769u).a;
      } else {
        const uint32_t mm = 2u * j - 32768u;
        key.a = tf2x32(0u, 42u, mm,      mm + 32768u).b;
        key.b = tf2x32(0u, 42u, mm + 1u, mm + 32769u).b;
      }
    }
#endif

    float xi = 0.0f;
    bool done = false;
    for (int it = 0; it < 100000 && !done; ++it) {
#if PARTITIONABLE
      const U2 kn = tf2x32(key.a, key.b, 0u, 0u);   // split(k,3)[0]
      const U2 k1 = tf2x32(key.a, key.b, 0u, 1u);   // split(k,3)[1]
      const U2 k2 = tf2x32(key.a, key.b, 0u, 2u);   // split(k,3)[2]
      // partitionable 32-bit random_bits = XOR of the two output words
      const U2 ru = tf2x32(k1.a, k1.b, 0u, 0u);
      const U2 rx = tf2x32(k2.a, k2.b, 0u, 0u);
      const uint32_t bu = ru.a ^ ru.b;
      const uint32_t bx = rx.a ^ rx.b;
#else
      const U2 p0 = tf2x32(key.a, key.b, 0u, 3u);
      const U2 p1 = tf2x32(key.a, key.b, 1u, 4u);
      const U2 p2 = tf2x32(key.a, key.b, 2u, 5u);
      const U2 kn = {p0.a, p1.a};
      const U2 k1 = {p2.a, p0.b};
      const U2 k2 = {p1.b, p2.b};
      const uint32_t bu = tf2x32(k1.a, k1.b, 0u, 0u).a;  // legacy: first word
      const uint32_t bx = tf2x32(k2.a, k2.b, 0u, 0u).a;
#endif
      const float u  = bits_to_u01(bu);
      const float u2 = bits_to_u01(bx);
      xi = 2.0f * u2 - 1.0f;   // exact: 2*u2 is exact, single rounding
      const double dxi = (double)xi;
      // nll = 0.5/512 * (A + Q - 2*xi*M + xi^2*I)
      const double nx = (0.5 / 512.0) * (Ax + Qx + dxi * (dxi * Ix - 2.0 * Mx));
      const double ny = (0.5 / 512.0) * (Ay + Qy + dxi * (dxi * Iy - 2.0 * My));
      done = ((double)u >= nx * ny);
      key = kn;
    }
    out[grow] = fminf(fmaxf(xi, 1e-5f), 10.0f);
  }
}

extern "C" void kernel_launch(void* const* d_in, const int* in_sizes, int n_in,
                              void* d_out, int out_size, void* d_ws, size_t ws_size,
                              hipStream_t stream) {
  const float* x    = (const float*)d_in[0];
  const float* y    = (const float*)d_in[1];
  const float* Wmux = (const float*)d_in[2];
  const float* bmux = (const float*)d_in[3];
  const float* Wsgx = (const float*)d_in[4];
  const float* bsgx = (const float*)d_in[5];
  const float* Wmuy = (const float*)d_in[6];
  const float* bmuy = (const float*)d_in[7];
  const float* Wsgy = (const float*)d_in[8];
  const float* bsgy = (const float*)d_in[9];
  (void)in_sizes; (void)n_in; (void)d_ws; (void)ws_size; (void)out_size;

  fused_proposal_kernel<<<32768 / TM, 256, 0, stream>>>(
      x, y, Wmux, bmux, Wsgx, bsgx, Wmuy, bmuy, Wsgy, bsgy, (float*)d_out);
}